// Round 8
// baseline (562.385 us; speedup 1.0000x reference)
//
#include <hip/hip_runtime.h>

// C[b,i] = 0.125 * sum_k LI[X[b,8,3]][k] * IL[i][k]
// M=1024, N=100000, K=64.
//
// DIAGNOSTIC v6 (base = R3's v2b verbatim, the session-best measured structure):
// ONE change vs the R6 diagnostic: __builtin_nontemporal_store -> plain cached
// stores.  REPS=2 so the gemm dispatch (~2x ~110-150 us) surfaces above the
// ~260 us harness fills in the top-5 counter table.  A/B vs R6's NT counters:
//   NT/pass:  dur ~145 us, WRITE 545 MB (1.36x), 4.2 TB/s, occ 31%
//   predict cached/pass: dur ~100-115, WRITE ~420 MB (1.0x), >=5 TB/s, occ >=40%

#define REPS 2

typedef short short8 __attribute__((ext_vector_type(8)));
typedef float f32x4 __attribute__((ext_vector_type(4)));
typedef unsigned short ushort4v __attribute__((ext_vector_type(4)));
typedef unsigned short ushort8v __attribute__((ext_vector_type(8)));

#define KDIM  64
#define LDSS  72     // padded LDS row stride in bf16 (144 B -> 2-way bank alias only, free)
#define MSLAB 256    // A rows resident in LDS per block
#define NSLAB 256    // output columns per block
#define NCH   32     // columns per inner chunk

static __device__ __forceinline__ unsigned short f2bf(float f) {
    unsigned u = __float_as_uint(f);
    return (unsigned short)((u + 0x7fffu + ((u >> 16) & 1u)) >> 16);   // RNE
}

static __device__ __forceinline__ short8 cvt8(float4 v0, float4 v1) {
    union { ushort8v u; short8 s; } r;
    r.u[0] = f2bf(v0.x); r.u[1] = f2bf(v0.y); r.u[2] = f2bf(v0.z); r.u[3] = f2bf(v0.w);
    r.u[4] = f2bf(v1.x); r.u[5] = f2bf(v1.y); r.u[6] = f2bf(v1.z); r.u[7] = f2bf(v1.w);
    return r.s;
}

// ---- Phase 1: A[b][k] = bf16(LI[X[b,8,3]][k]) into ws. ----
__global__ __launch_bounds__(256)
void fpmc_gather(const int* __restrict__ X, const float* __restrict__ LI,
                 unsigned short* __restrict__ ws, int M) {
    const int t = threadIdx.x;
    const int r = blockIdx.x * 16 + (t >> 4);
    if (r >= M) return;
    const int c = (t & 15) * 4;
    const int idx = X[r * 40 + 35];                    // X[b, 8, 3]
    const float4 v = *(const float4*)(LI + (size_t)idx * KDIM + c);
    ushort4v p;
    p.x = f2bf(v.x); p.y = f2bf(v.y); p.z = f2bf(v.z); p.w = f2bf(v.w);
    *(ushort4v*)(ws + (size_t)r * KDIM + c) = p;
}

// ---- Phase 2: stream IL, MFMA vs LDS-resident A-slab, CACHED stores. x REPS ----
template<bool USE_WS>
__global__ __launch_bounds__(256, 4)
void fpmc_gemm2(const int* __restrict__ X, const float* __restrict__ IL,
                const float* __restrict__ LI, const unsigned short* __restrict__ Aws,
                float* __restrict__ out, int M, int N) {
    __shared__ __align__(16) unsigned short As[MSLAB * LDSS];   // 36,864 B -> 4 blocks/CU

    const int t  = threadIdx.x;
    const int m0 = blockIdx.y * MSLAB;
    const int i0 = blockIdx.x * NSLAB;

    if (USE_WS) {
        #pragma unroll
        for (int it = 0; it < 8; ++it) {
            const int chunk = it * 256 + t;
            const int r = chunk >> 3;
            const int c = (chunk & 7) * 8;
            ushort8v v = *(const ushort8v*)(Aws + (size_t)(m0 + r) * KDIM + c);
            *(ushort8v*)&As[r * LDSS + c] = v;
        }
    } else {
        const int rb = t >> 4;
        const int c  = (t & 15) * 4;
        #pragma unroll
        for (int it = 0; it < MSLAB / 16; ++it) {
            const int r = it * 16 + rb;
            const int idx = X[(m0 + r) * 40 + 35];
            const float4 v = *(const float4*)(LI + (size_t)idx * KDIM + c);
            ushort4v p;
            p.x = f2bf(v.x); p.y = f2bf(v.y); p.z = f2bf(v.z); p.w = f2bf(v.w);
            *(ushort4v*)&As[r * LDSS + c] = p;
        }
    }
    __syncthreads();

    const int w    = t >> 6;
    const int l    = t & 63;
    const int lr   = l & 15;
    const int quad = l >> 4;
    const int mwav = w * 64;
    const float scale = 0.125f;

    #pragma unroll 1
    for (int rep = 0; rep < REPS; ++rep) {
        #pragma unroll 1
        for (int nc = 0; nc < NSLAB / NCH; ++nc) {
            const int n0c = i0 + nc * NCH;

            f32x4 acc[4][2];
            #pragma unroll
            for (int mt = 0; mt < 4; ++mt)
                #pragma unroll
                for (int nt = 0; nt < 2; ++nt)
                    acc[mt][nt] = (f32x4){0.f, 0.f, 0.f, 0.f};

            #pragma unroll
            for (int ks = 0; ks < 2; ++ks) {
                short8 b[2];
                #pragma unroll
                for (int nt = 0; nt < 2; ++nt) {
                    int n = n0c + nt * 16 + lr;
                    if (n > N - 1) n = N - 1;          // clamp; stores guarded below
                    const float* p = IL + (size_t)n * KDIM + ks * 32 + quad * 8;
                    b[nt] = cvt8(*(const float4*)p, *(const float4*)(p + 4));
                }
                short8 a[4];
                #pragma unroll
                for (int mt = 0; mt < 4; ++mt)
                    a[mt] = *(const short8*)&As[(mwav + mt * 16 + lr) * LDSS + ks * 32 + quad * 8];
                #pragma unroll
                for (int mt = 0; mt < 4; ++mt)
                    #pragma unroll
                    for (int nt = 0; nt < 2; ++nt)
                        acc[mt][nt] = __builtin_amdgcn_mfma_f32_16x16x32_bf16(
                            b[nt], a[mt], acc[mt][nt], 0, 0, 0);
            }

            // CACHED stores: nt=0/1 back-to-back from the same wave assemble
            // each 128B line in L2; full-line eviction, L2-latency completion.
            #pragma unroll
            for (int mt = 0; mt < 4; ++mt) {
                const int m = m0 + mwav + mt * 16 + lr;
                float* orow = out + (size_t)m * N;
                #pragma unroll
                for (int nt = 0; nt < 2; ++nt) {
                    const int n = n0c + nt * 16 + quad * 4;
                    if (n < N)                          // N%4==0 -> whole-f32x4 guard
                        *(f32x4*)(orow + n) = acc[mt][nt] * scale;
                }
            }
        }
        // prevent CSE / dead-store elimination across passes
        asm volatile("" ::: "memory");
    }
}

extern "C" void kernel_launch(void* const* d_in, const int* in_sizes, int n_in,
                              void* d_out, int out_size, void* d_ws, size_t ws_size,
                              hipStream_t stream) {
    const int*   X  = (const int*)d_in[0];
    const float* IL = (const float*)d_in[1];
    const float* LI = (const float*)d_in[2];
    float* out = (float*)d_out;

    const int M = in_sizes[0] / 40;      // 1024
    const int N = in_sizes[1] / KDIM;    // 100000

    unsigned short* Aws = (unsigned short*)d_ws;
    const size_t need = (size_t)M * KDIM * sizeof(unsigned short);   // 128 KB

    dim3 grid((N + NSLAB - 1) / NSLAB, (M + MSLAB - 1) / MSLAB);
    if (d_ws != nullptr && ws_size >= need) {
        fpmc_gather<<<dim3((M + 15) / 16), dim3(256), 0, stream>>>(X, LI, Aws, M);
        fpmc_gemm2<true><<<grid, dim3(256), 0, stream>>>(X, IL, LI, Aws, out, M, N);
    } else {
        fpmc_gemm2<false><<<grid, dim3(256), 0, stream>>>(X, IL, LI, Aws, out, M, N);
    }
}

// Round 9
// 519.667 us; speedup vs baseline: 1.0822x; 1.0822x over previous
//
#include <hip/hip_runtime.h>

// C[b,i] = 0.125 * sum_k LI[X[b,8,3]][k] * IL[i][k]
// M=1024, N=100000, K=64.  Write-bound (409.6 MB out).
//
// v7 (commit): R6/R8 diagnostics proved NT stores cost 22% (write amplification
// 1.36x + DRAM-latency completion): NT 140 us/pass -> cached 109 us/pass.
// This version: cached stores, REPS=1, plus NCH 32->64 so each wave writes
// 256 B contiguous per row per iteration (two full adjacent 128 B L2 lines,
// halving the scattered-granule penalty at DRAM).  Base structure = R3 v2b
// (MSLAB=256, 4 blocks/CU — v5's MSLAB=128 decoded to ~158 us/pass, rejected).

typedef short short8 __attribute__((ext_vector_type(8)));
typedef float f32x4 __attribute__((ext_vector_type(4)));
typedef unsigned short ushort4v __attribute__((ext_vector_type(4)));
typedef unsigned short ushort8v __attribute__((ext_vector_type(8)));

#define KDIM  64
#define LDSS  72     // padded LDS row stride in bf16 (144 B -> 2-way bank alias only, free)
#define MSLAB 256    // A rows resident in LDS per block
#define NSLAB 256    // output columns per block
#define NCH   64     // columns per inner chunk (256 B/row contiguous stores)

static __device__ __forceinline__ unsigned short f2bf(float f) {
    unsigned u = __float_as_uint(f);
    return (unsigned short)((u + 0x7fffu + ((u >> 16) & 1u)) >> 16);   // RNE
}

static __device__ __forceinline__ short8 cvt8(float4 v0, float4 v1) {
    union { ushort8v u; short8 s; } r;
    r.u[0] = f2bf(v0.x); r.u[1] = f2bf(v0.y); r.u[2] = f2bf(v0.z); r.u[3] = f2bf(v0.w);
    r.u[4] = f2bf(v1.x); r.u[5] = f2bf(v1.y); r.u[6] = f2bf(v1.z); r.u[7] = f2bf(v1.w);
    return r.s;
}

// ---- Phase 1: A[b][k] = bf16(LI[X[b,8,3]][k]) into ws. ----
__global__ __launch_bounds__(256)
void fpmc_gather(const int* __restrict__ X, const float* __restrict__ LI,
                 unsigned short* __restrict__ ws, int M) {
    const int t = threadIdx.x;
    const int r = blockIdx.x * 16 + (t >> 4);
    if (r >= M) return;
    const int c = (t & 15) * 4;
    const int idx = X[r * 40 + 35];                    // X[b, 8, 3]
    const float4 v = *(const float4*)(LI + (size_t)idx * KDIM + c);
    ushort4v p;
    p.x = f2bf(v.x); p.y = f2bf(v.y); p.z = f2bf(v.z); p.w = f2bf(v.w);
    *(ushort4v*)(ws + (size_t)r * KDIM + c) = p;
}

// ---- Phase 2: stream IL, MFMA vs LDS-resident A-slab, cached 256B-run stores. ----
template<bool USE_WS>
__global__ __launch_bounds__(256, 4)
void fpmc_gemm2(const int* __restrict__ X, const float* __restrict__ IL,
                const float* __restrict__ LI, const unsigned short* __restrict__ Aws,
                float* __restrict__ out, int M, int N) {
    __shared__ __align__(16) unsigned short As[MSLAB * LDSS];   // 36,864 B -> 4 blocks/CU

    const int t  = threadIdx.x;
    const int m0 = blockIdx.y * MSLAB;
    const int i0 = blockIdx.x * NSLAB;

    if (USE_WS) {
        #pragma unroll
        for (int it = 0; it < 8; ++it) {
            const int chunk = it * 256 + t;
            const int r = chunk >> 3;
            const int c = (chunk & 7) * 8;
            ushort8v v = *(const ushort8v*)(Aws + (size_t)(m0 + r) * KDIM + c);
            *(ushort8v*)&As[r * LDSS + c] = v;
        }
    } else {
        const int rb = t >> 4;
        const int c  = (t & 15) * 4;
        #pragma unroll
        for (int it = 0; it < MSLAB / 16; ++it) {
            const int r = it * 16 + rb;
            const int idx = X[(m0 + r) * 40 + 35];
            const float4 v = *(const float4*)(LI + (size_t)idx * KDIM + c);
            ushort4v p;
            p.x = f2bf(v.x); p.y = f2bf(v.y); p.z = f2bf(v.z); p.w = f2bf(v.w);
            *(ushort4v*)&As[r * LDSS + c] = p;
        }
    }
    __syncthreads();

    const int w    = t >> 6;
    const int l    = t & 63;
    const int lr   = l & 15;
    const int quad = l >> 4;
    const int mwav = w * 64;
    const float scale = 0.125f;

    #pragma unroll 1
    for (int nc = 0; nc < NSLAB / NCH; ++nc) {
        const int n0c = i0 + nc * NCH;

        f32x4 acc[4][4];
        #pragma unroll
        for (int mt = 0; mt < 4; ++mt)
            #pragma unroll
            for (int nt = 0; nt < 4; ++nt)
                acc[mt][nt] = (f32x4){0.f, 0.f, 0.f, 0.f};

        #pragma unroll
        for (int ks = 0; ks < 2; ++ks) {
            short8 b[4];
            #pragma unroll
            for (int nt = 0; nt < 4; ++nt) {
                int n = n0c + nt * 16 + lr;
                if (n > N - 1) n = N - 1;              // clamp; stores guarded below
                const float* p = IL + (size_t)n * KDIM + ks * 32 + quad * 8;
                b[nt] = cvt8(*(const float4*)p, *(const float4*)(p + 4));
            }
            short8 a[4];
            #pragma unroll
            for (int mt = 0; mt < 4; ++mt)
                a[mt] = *(const short8*)&As[(mwav + mt * 16 + lr) * LDSS + ks * 32 + quad * 8];
            #pragma unroll
            for (int mt = 0; mt < 4; ++mt)
                #pragma unroll
                for (int nt = 0; nt < 4; ++nt)
                    acc[mt][nt] = __builtin_amdgcn_mfma_f32_16x16x32_bf16(
                        b[nt], a[mt], acc[mt][nt], 0, 0, 0);
        }

        // cached stores: per row (m), the four nt instructions are back-to-back
        // and cover 256 B contiguous -> two full adjacent 128 B lines assemble
        // in L2 and evict as whole lines.
        #pragma unroll
        for (int mt = 0; mt < 4; ++mt) {
            const int m = m0 + mwav + mt * 16 + lr;
            float* orow = out + (size_t)m * N;
            #pragma unroll
            for (int nt = 0; nt < 4; ++nt) {
                const int n = n0c + nt * 16 + quad * 4;
                if (n < N)                              // N%16==0 -> whole-f32x4 guard
                    *(f32x4*)(orow + n) = acc[mt][nt] * scale;
            }
        }
    }
}

extern "C" void kernel_launch(void* const* d_in, const int* in_sizes, int n_in,
                              void* d_out, int out_size, void* d_ws, size_t ws_size,
                              hipStream_t stream) {
    const int*   X  = (const int*)d_in[0];
    const float* IL = (const float*)d_in[1];
    const float* LI = (const float*)d_in[2];
    float* out = (float*)d_out;

    const int M = in_sizes[0] / 40;      // 1024
    const int N = in_sizes[1] / KDIM;    // 100000

    unsigned short* Aws = (unsigned short*)d_ws;
    const size_t need = (size_t)M * KDIM * sizeof(unsigned short);   // 128 KB

    dim3 grid((N + NSLAB - 1) / NSLAB, (M + MSLAB - 1) / MSLAB);
    if (d_ws != nullptr && ws_size >= need) {
        fpmc_gather<<<dim3((M + 15) / 16), dim3(256), 0, stream>>>(X, LI, Aws, M);
        fpmc_gemm2<true><<<grid, dim3(256), 0, stream>>>(X, IL, LI, Aws, out, M, N);
    } else {
        fpmc_gemm2<false><<<grid, dim3(256), 0, stream>>>(X, IL, LI, Aws, out, M, N);
    }
}

// Round 10
// 468.519 us; speedup vs baseline: 1.2003x; 1.1092x over previous
//
#include <hip/hip_runtime.h>

// C[b,i] = 0.125 * sum_k LI[X[b,8,3]][k] * IL[i][k]
// M=1024, N=100000, K=64.  Write-bound (409.6 MB out).
//
// v8 (commit, = R8 kernel at REPS=1): R6/R8 A/B proved NT stores cost 22%
// (1.36x write amplification + DRAM-latency completion in the vmcnt queue):
// NT 140 us/pass -> cached 109 us/pass.  R9 proved NCH=64 regresses (176/pass,
// register-pressure cliff) -> NCH=32 retained.  Structure = R3 v2b: one-time
// bf16 A-gather to ws, 256-row A-slab in LDS, IL streamed global->reg,
// cached f32x4 stores (back-to-back nt pairs assemble full 128B L2 lines).

#define REPS 1

typedef short short8 __attribute__((ext_vector_type(8)));
typedef float f32x4 __attribute__((ext_vector_type(4)));
typedef unsigned short ushort4v __attribute__((ext_vector_type(4)));
typedef unsigned short ushort8v __attribute__((ext_vector_type(8)));

#define KDIM  64
#define LDSS  72     // padded LDS row stride in bf16 (144 B -> 2-way bank alias only, free)
#define MSLAB 256    // A rows resident in LDS per block
#define NSLAB 256    // output columns per block
#define NCH   32     // columns per inner chunk

static __device__ __forceinline__ unsigned short f2bf(float f) {
    unsigned u = __float_as_uint(f);
    return (unsigned short)((u + 0x7fffu + ((u >> 16) & 1u)) >> 16);   // RNE
}

static __device__ __forceinline__ short8 cvt8(float4 v0, float4 v1) {
    union { ushort8v u; short8 s; } r;
    r.u[0] = f2bf(v0.x); r.u[1] = f2bf(v0.y); r.u[2] = f2bf(v0.z); r.u[3] = f2bf(v0.w);
    r.u[4] = f2bf(v1.x); r.u[5] = f2bf(v1.y); r.u[6] = f2bf(v1.z); r.u[7] = f2bf(v1.w);
    return r.s;
}

// ---- Phase 1: A[b][k] = bf16(LI[X[b,8,3]][k]) into ws. ----
__global__ __launch_bounds__(256)
void fpmc_gather(const int* __restrict__ X, const float* __restrict__ LI,
                 unsigned short* __restrict__ ws, int M) {
    const int t = threadIdx.x;
    const int r = blockIdx.x * 16 + (t >> 4);
    if (r >= M) return;
    const int c = (t & 15) * 4;
    const int idx = X[r * 40 + 35];                    // X[b, 8, 3]
    const float4 v = *(const float4*)(LI + (size_t)idx * KDIM + c);
    ushort4v p;
    p.x = f2bf(v.x); p.y = f2bf(v.y); p.z = f2bf(v.z); p.w = f2bf(v.w);
    *(ushort4v*)(ws + (size_t)r * KDIM + c) = p;
}

// ---- Phase 2: stream IL, MFMA vs LDS-resident A-slab, CACHED stores. ----
template<bool USE_WS>
__global__ __launch_bounds__(256, 4)
void fpmc_gemm2(const int* __restrict__ X, const float* __restrict__ IL,
                const float* __restrict__ LI, const unsigned short* __restrict__ Aws,
                float* __restrict__ out, int M, int N) {
    __shared__ __align__(16) unsigned short As[MSLAB * LDSS];   // 36,864 B -> 4 blocks/CU

    const int t  = threadIdx.x;
    const int m0 = blockIdx.y * MSLAB;
    const int i0 = blockIdx.x * NSLAB;

    if (USE_WS) {
        #pragma unroll
        for (int it = 0; it < 8; ++it) {
            const int chunk = it * 256 + t;
            const int r = chunk >> 3;
            const int c = (chunk & 7) * 8;
            ushort8v v = *(const ushort8v*)(Aws + (size_t)(m0 + r) * KDIM + c);
            *(ushort8v*)&As[r * LDSS + c] = v;
        }
    } else {
        const int rb = t >> 4;
        const int c  = (t & 15) * 4;
        #pragma unroll
        for (int it = 0; it < MSLAB / 16; ++it) {
            const int r = it * 16 + rb;
            const int idx = X[(m0 + r) * 40 + 35];
            const float4 v = *(const float4*)(LI + (size_t)idx * KDIM + c);
            ushort4v p;
            p.x = f2bf(v.x); p.y = f2bf(v.y); p.z = f2bf(v.z); p.w = f2bf(v.w);
            *(ushort4v*)&As[r * LDSS + c] = p;
        }
    }
    __syncthreads();

    const int w    = t >> 6;
    const int l    = t & 63;
    const int lr   = l & 15;
    const int quad = l >> 4;
    const int mwav = w * 64;
    const float scale = 0.125f;

    #pragma unroll 1
    for (int rep = 0; rep < REPS; ++rep) {
        #pragma unroll 1
        for (int nc = 0; nc < NSLAB / NCH; ++nc) {
            const int n0c = i0 + nc * NCH;

            f32x4 acc[4][2];
            #pragma unroll
            for (int mt = 0; mt < 4; ++mt)
                #pragma unroll
                for (int nt = 0; nt < 2; ++nt)
                    acc[mt][nt] = (f32x4){0.f, 0.f, 0.f, 0.f};

            #pragma unroll
            for (int ks = 0; ks < 2; ++ks) {
                short8 b[2];
                #pragma unroll
                for (int nt = 0; nt < 2; ++nt) {
                    int n = n0c + nt * 16 + lr;
                    if (n > N - 1) n = N - 1;          // clamp; stores guarded below
                    const float* p = IL + (size_t)n * KDIM + ks * 32 + quad * 8;
                    b[nt] = cvt8(*(const float4*)p, *(const float4*)(p + 4));
                }
                short8 a[4];
                #pragma unroll
                for (int mt = 0; mt < 4; ++mt)
                    a[mt] = *(const short8*)&As[(mwav + mt * 16 + lr) * LDSS + ks * 32 + quad * 8];
                #pragma unroll
                for (int mt = 0; mt < 4; ++mt)
                    #pragma unroll
                    for (int nt = 0; nt < 2; ++nt)
                        acc[mt][nt] = __builtin_amdgcn_mfma_f32_16x16x32_bf16(
                            b[nt], a[mt], acc[mt][nt], 0, 0, 0);
            }

            // CACHED stores: nt=0/1 back-to-back from the same wave assemble
            // each 128B line in L2; full-line eviction, L2-latency completion.
            #pragma unroll
            for (int mt = 0; mt < 4; ++mt) {
                const int m = m0 + mwav + mt * 16 + lr;
                float* orow = out + (size_t)m * N;
                #pragma unroll
                for (int nt = 0; nt < 2; ++nt) {
                    const int n = n0c + nt * 16 + quad * 4;
                    if (n < N)                          // N%4==0 -> whole-f32x4 guard
                        *(f32x4*)(orow + n) = acc[mt][nt] * scale;
                }
            }
        }
        asm volatile("" ::: "memory");
    }
}

extern "C" void kernel_launch(void* const* d_in, const int* in_sizes, int n_in,
                              void* d_out, int out_size, void* d_ws, size_t ws_size,
                              hipStream_t stream) {
    const int*   X  = (const int*)d_in[0];
    const float* IL = (const float*)d_in[1];
    const float* LI = (const float*)d_in[2];
    float* out = (float*)d_out;

    const int M = in_sizes[0] / 40;      // 1024
    const int N = in_sizes[1] / KDIM;    // 100000

    unsigned short* Aws = (unsigned short*)d_ws;
    const size_t need = (size_t)M * KDIM * sizeof(unsigned short);   // 128 KB

    dim3 grid((N + NSLAB - 1) / NSLAB, (M + MSLAB - 1) / MSLAB);
    if (d_ws != nullptr && ws_size >= need) {
        fpmc_gather<<<dim3((M + 15) / 16), dim3(256), 0, stream>>>(X, LI, Aws, M);
        fpmc_gemm2<true><<<grid, dim3(256), 0, stream>>>(X, IL, LI, Aws, out, M, N);
    } else {
        fpmc_gemm2<false><<<grid, dim3(256), 0, stream>>>(X, IL, LI, Aws, out, M, N);
    }
}